// Round 7
// baseline (476.700 us; speedup 1.0000x reference)
//
#include <hip/hip_runtime.h>

typedef __bf16 bf16x8 __attribute__((ext_vector_type(8)));
typedef __bf16 bf16x4 __attribute__((ext_vector_type(4)));
typedef float f32x4 __attribute__((ext_vector_type(4)));

#define S_BARRIER() asm volatile("s_barrier" ::: "memory")
#define WAITCNT_VM(n) asm volatile("s_waitcnt vmcnt(" #n ")" ::: "memory")
#define WAITCNT_LGKM0() asm volatile("s_waitcnt lgkmcnt(0)" ::: "memory")

// ---------------------------------------------------------------------------
// Weight prep (LN fused into down-proj GEMM).
// Blocks [0, ntile_d): W_down transpose with gamma folded: Wtd[n][k] =
//   bf16(gamma[k]*Wd[k][n]);  C1[n] += sum_k float(bf16(gamma[k]*W[k][n]));
//   C2b[n] += sum_k beta[k]*W[k][n]  (C2b pre-seeded with b_down).
// Blocks [ntile_d, 2*ntile_d): plain W_up transpose -> bf16 Wtu[d][k].
// ---------------------------------------------------------------------------
__global__ __launch_bounds__(256) void prep_w_kernel(
    const float* __restrict__ Wd, __bf16* __restrict__ Wtd,
    const float* __restrict__ Wu, __bf16* __restrict__ Wtu,
    const float* __restrict__ g, const float* __restrict__ be,
    float* __restrict__ C1, float* __restrict__ C2b,
    int D, int Db) {
    const int ntile_d = (Db / 32) * (D / 32);
    __shared__ float t[32][33];
    const int c = threadIdx.x & 31, r0 = threadIdx.x >> 5;
    if ((int)blockIdx.x < ntile_d) {
        const int K = D, N = Db, tile = blockIdx.x;
        const int tn = tile % (N / 32), tk = tile / (N / 32);
        const int n0 = tn * 32, k0 = tk * 32;
#pragma unroll
        for (int r = r0; r < 32; r += 8)
            t[r][c] = Wd[(size_t)(k0 + r) * N + n0 + c];
        __syncthreads();
        const float gv = g[k0 + c];
        const float bv = be[k0 + c];
        float c1p[4], c2p[4];
#pragma unroll
        for (int u = 0; u < 4; ++u) {
            const int r = r0 + u * 8;
            const float wv = t[c][r];
            const __bf16 w16 = (__bf16)(gv * wv);
            Wtd[(size_t)(n0 + r) * K + k0 + c] = w16;
            c1p[u] = (float)w16;
            c2p[u] = bv * wv;
        }
#pragma unroll
        for (int o = 16; o > 0; o >>= 1)
#pragma unroll
            for (int u = 0; u < 4; ++u) {
                c1p[u] += __shfl_xor(c1p[u], o);
                c2p[u] += __shfl_xor(c2p[u], o);
            }
        if (c == 0)
#pragma unroll
            for (int u = 0; u < 4; ++u) {
                atomicAdd(&C1[n0 + r0 + u * 8], c1p[u]);
                atomicAdd(&C2b[n0 + r0 + u * 8], c2p[u]);
            }
    } else {
        const int K = Db, N = D, tile = blockIdx.x - ntile_d;
        const int tn = tile % (N / 32), tk = tile / (N / 32);
        const int n0 = tn * 32, k0 = tk * 32;
#pragma unroll
        for (int r = r0; r < 32; r += 8)
            t[r][c] = Wu[(size_t)(k0 + r) * N + n0 + c];
        __syncthreads();
#pragma unroll
        for (int r = r0; r < 32; r += 8)
            Wtu[(size_t)(n0 + r) * K + k0 + c] = (__bf16)t[c][r];
    }
}

// ---------------------------------------------------------------------------
// FUSED LayerNorm + down-proj + SiLU.  BK=64, kb-half as OUTER LDS dim.
//   z = silu( rstd*acc - (rstd*mu)*C1[n] + C2b[n] )
// LAYOUT FIX (r6 NaN): global_load_lds writes base+lane*16 LINEARLY, so each
// DMA destination must be a contiguous 16-row x 32-elem panel (stride 32).
// With BK=64 that requires the 32-elem kb-half as a separate outer dimension:
//   Bds[buf][kb][BN*32], Ads[kb][BM*32].  Readers index [kb] accordingly.
// - X loaded NON-TEMPORAL (134MB stream must not evict 2MB weight panels
//   from per-XCD L2 -> targets r4's 264MB FETCH) and z stored non-temporal.
// - A reg-staged: 64B/lane/iter fp32 -> cast bf16 -> single-buffer LDS.
// - B via global_load_lds dbuf, 4 DMAs/wave/iter; counted vmcnt(8) keeps the
//   next tile's 4 DMAs + 4 A-loads in flight across the barrier.
// - Row stats accumulate AFTER the MFMA block (off the critical path); exact
//   coverage: thread owns row arow, chunk (lane&3)^(lrow&3) per 32-half.
// - XOR chunk swizzle: LDS slot s holds global chunk s^(row&3); reader uses
//   q^(c&3) (valid since rl&3 == c&3: all row offsets are multiples of 4).
// 64x128 tile, 1024 blocks, ~40.5KB LDS -> 3 blocks/CU.
// ---------------------------------------------------------------------------
__global__ __launch_bounds__(256, 3) void fused_ln_down(
    const float* __restrict__ X, const __bf16* __restrict__ Bt,
    const float* __restrict__ C1, const float* __restrict__ C2b,
    __bf16* __restrict__ Z, int M, int N, int K) {
    constexpr int BM = 64, BN = 128, BK = 64;
    constexpr int WM = 32, WN = 64, MI = 2, NJ = 4;
    __shared__ __align__(16) __bf16 Ads[2][BM * 32];      // [kb][row*32]
    __shared__ __align__(16) __bf16 Bds[2][2][BN * 32];   // [buf][kb][row*32]
    __shared__ float sRow[BM], ssRow[BM];

    const int tid = threadIdx.x;
    const int wave = tid >> 6, lane = tid & 63;
    const int bn = blockIdx.x, bm = blockIdx.y;
    const int row0 = bm * BM, col0 = bn * BN;
    const int wr = wave >> 1, wc = wave & 1;

    f32x4 acc[MI][NJ] = {};

    const int lrow = lane >> 2;                 // 0..15
    const int chunk = (lane & 3) ^ (lrow & 3);  // global k-chunk (per 32-half)
    const int arow = wave * 16 + lrow;          // 0..63: this thread's A row
    const float* Axr = X + (size_t)(row0 + arow) * K + chunk * 8;
    const __bf16* Bg = Bt + (size_t)col0 * K;
    const int lk = chunk * 8;

    const int c = lane & 15, q = lane >> 4;

    auto stageB = [&](int k0, int b) {
#pragma unroll
        for (int p = 0; p < 2; ++p) {
            const int r = wave * 32 + p * 16;  // wave-uniform B 16-row group
#pragma unroll
            for (int kb = 0; kb < 2; ++kb) {
                __builtin_amdgcn_global_load_lds(
                    (__attribute__((address_space(1))) void*)(Bg + (size_t)(r + lrow) * K + k0 + kb * 32 + lk),
                    (__attribute__((address_space(3))) void*)(&Bds[b][kb][r * 32]),
                    16, 0, 0);
            }
        }
    };

    auto ldA = [&](int it, f32x4* d) {
#pragma unroll
        for (int kb = 0; kb < 2; ++kb) {
            d[kb * 2] = __builtin_nontemporal_load((const f32x4*)(Axr + it * BK + kb * 32));
            d[kb * 2 + 1] = __builtin_nontemporal_load((const f32x4*)(Axr + it * BK + kb * 32 + 4));
        }
    };

    float s = 0.f, ss = 0.f;
    const int nk = K / BK;  // 32
    stageB(0, 0);
    f32x4 a[4];
    ldA(0, a);
    for (int it = 0; it < nk; ++it) {
        const int cur = it & 1;
        f32x4 nx[4];
        if (it + 1 < nk) {
            stageB((it + 1) * BK, cur ^ 1);
            ldA(it + 1, nx);
            WAITCNT_VM(8);  // 8 newest (next tile's 4 DMA + 4 loads) in flight
        } else {
            WAITCNT_VM(0);
        }
        // cast + LDS write of current A chunks (slot = lane&3 per 32-half)
#pragma unroll
        for (int kb = 0; kb < 2; ++kb) {
            bf16x8 av;
            av[0] = (__bf16)a[kb * 2][0]; av[1] = (__bf16)a[kb * 2][1];
            av[2] = (__bf16)a[kb * 2][2]; av[3] = (__bf16)a[kb * 2][3];
            av[4] = (__bf16)a[kb * 2 + 1][0]; av[5] = (__bf16)a[kb * 2 + 1][1];
            av[6] = (__bf16)a[kb * 2 + 1][2]; av[7] = (__bf16)a[kb * 2 + 1][3];
            *(bf16x8*)(&Ads[kb][arow * 32 + (lane & 3) * 8]) = av;
        }
        WAITCNT_LGKM0();  // my ds_writes retired
        S_BARRIER();      // all waves: A written, B(cur) DMA landed

#pragma unroll
        for (int kb = 0; kb < 2; ++kb) {
            bf16x8 afW[NJ], bfA[MI];
#pragma unroll
            for (int j = 0; j < NJ; ++j) {
                const int rl = wc * WN + j * 16 + c;
                afW[j] = *(const bf16x8*)(&Bds[cur][kb][rl * 32 + ((q ^ (c & 3)) * 8)]);
            }
#pragma unroll
            for (int i = 0; i < MI; ++i) {
                const int rl = wr * WM + i * 16 + c;
                bfA[i] = *(const bf16x8*)(&Ads[kb][rl * 32 + ((q ^ (c & 3)) * 8)]);
            }
#pragma unroll
            for (int i = 0; i < MI; ++i)
#pragma unroll
                for (int j = 0; j < NJ; ++j)
                    acc[i][j] = __builtin_amdgcn_mfma_f32_16x16x32_bf16(afW[j], bfA[i],
                                                                        acc[i][j], 0, 0, 0);
        }
        // stats AFTER MFMA issue: independent VALU, overlaps matrix pipe
#pragma unroll
        for (int u = 0; u < 4; ++u) {
            s += a[u][0] + a[u][1] + a[u][2] + a[u][3];
            ss += a[u][0] * a[u][0] + a[u][1] * a[u][1] +
                  a[u][2] * a[u][2] + a[u][3] * a[u][3];
        }
        WAITCNT_LGKM0();  // my LDS reads retired
        S_BARRIER();      // buffers safe to overwrite next iteration
#pragma unroll
        for (int u = 0; u < 4; ++u) a[u] = nx[u];
    }

    // finalize row stats: reduce over lane bits 0-1 (the 4 chunk-lanes)
    s += __shfl_xor(s, 1);  s += __shfl_xor(s, 2);
    ss += __shfl_xor(ss, 1); ss += __shfl_xor(ss, 2);
    if ((lane & 3) == 0) { sRow[arow] = s; ssRow[arow] = ss; }
    __syncthreads();

    const float rK = 1.f / (float)K;
#pragma unroll
    for (int i = 0; i < MI; ++i) {
        const int rl = wr * WM + i * 16 + c;
        const float mu = sRow[rl] * rK;
        const float var = ssRow[rl] * rK - mu * mu;
        const float rstd = rsqrtf(var + 1e-5f);
        const float mrs = mu * rstd;
        const int rowg = row0 + rl;
#pragma unroll
        for (int j = 0; j < NJ; ++j) {
            const int colb = col0 + wc * WN + j * 16 + q * 4;
            const f32x4 c1 = *(const f32x4*)(C1 + colb);
            const f32x4 c2 = *(const f32x4*)(C2b + colb);
            float v0 = rstd * acc[i][j][0] - mrs * c1[0] + c2[0];
            float v1 = rstd * acc[i][j][1] - mrs * c1[1] + c2[1];
            float v2 = rstd * acc[i][j][2] - mrs * c1[2] + c2[2];
            float v3 = rstd * acc[i][j][3] - mrs * c1[3] + c2[3];
            bf16x4 o;
            o[0] = (__bf16)(v0 / (1.f + __expf(-v0)));
            o[1] = (__bf16)(v1 / (1.f + __expf(-v1)));
            o[2] = (__bf16)(v2 / (1.f + __expf(-v2)));
            o[3] = (__bf16)(v3 / (1.f + __expf(-v3)));
            __builtin_nontemporal_store(o, (bf16x4*)(Z + (size_t)rowg * N + colb));
        }
    }
}

// ---------------------------------------------------------------------------
// Up-proj GEMM: BK=32 dbuf LDS global_load_lds schedule (proven), XOR chunk
// swizzle, operand-swap MFMA. Residual epilogue: hid loaded NON-TEMPORAL and
// out stored NON-TEMPORAL (both touched once; keeps z + Wtu L2-resident).
// ---------------------------------------------------------------------------
template <int EPI, int BM, int BN, int MINW>
__global__ __launch_bounds__(256, MINW) void gemm_bt(
    const __bf16* __restrict__ A, const __bf16* __restrict__ Bt,
    const float* __restrict__ bias, const float* __restrict__ hid,
    const float* __restrict__ alpha_p, void* __restrict__ Cout,
    int M, int N, int K) {
    constexpr int BK = 32;
    constexpr int WM = BM / 2, WN = BN / 2;
    constexpr int MI = WM / 16, NJ = WN / 16;
    constexpr int GA = BM / 64, GB = BN / 64;
    constexpr int L = GA + GB;
    __shared__ __align__(16) __bf16 Ads[2][BM * BK];
    __shared__ __align__(16) __bf16 Bds[2][BN * BK];

    const int tid = threadIdx.x;
    const int wave = tid >> 6;
    const int lane = tid & 63;
    const int bn = blockIdx.x, bm = blockIdx.y;
    const int row0 = bm * BM, col0 = bn * BN;
    const int wr = wave >> 1, wc = wave & 1;

    f32x4 acc[MI][NJ] = {};

    const __bf16* Ag = A + (size_t)row0 * K;
    const __bf16* Bg = Bt + (size_t)col0 * K;
    const int lrow = lane >> 2;
    const int lk = ((lane & 3) ^ (lrow & 3)) * 8;

    const int c = lane & 15;
    const int q = lane >> 4;

    auto stage = [&](int k0, int b) {
#pragma unroll
        for (int p = 0; p < GA; ++p) {
            const int r = wave * (16 * GA) + p * 16;
            __builtin_amdgcn_global_load_lds(
                (__attribute__((address_space(1))) void*)(Ag + (size_t)(r + lrow) * K + k0 + lk),
                (__attribute__((address_space(3))) void*)(&Ads[b][r * BK]),
                16, 0, 0);
        }
#pragma unroll
        for (int p = 0; p < GB; ++p) {
            const int r = wave * (16 * GB) + p * 16;
            __builtin_amdgcn_global_load_lds(
                (__attribute__((address_space(1))) void*)(Bg + (size_t)(r + lrow) * K + k0 + lk),
                (__attribute__((address_space(3))) void*)(&Bds[b][r * BK]),
                16, 0, 0);
        }
    };

    const int nk = K / BK;
    stage(0, 0);
    for (int it = 0; it < nk; ++it) {
        const int cur = it & 1;
        if (it + 1 < nk) {
            stage((it + 1) * BK, cur ^ 1);
            if constexpr (L == 3) WAITCNT_VM(3); else WAITCNT_VM(4);
        } else {
            WAITCNT_VM(0);
        }
        S_BARRIER();

        bf16x8 afW[NJ], bfA[MI];
#pragma unroll
        for (int j = 0; j < NJ; ++j) {
            const int rl = wc * WN + j * 16 + c;
            afW[j] = *(const bf16x8*)(&Bds[cur][rl * BK + ((q ^ (c & 3)) * 8)]);
        }
#pragma unroll
        for (int i = 0; i < MI; ++i) {
            const int rl = wr * WM + i * 16 + c;
            bfA[i] = *(const bf16x8*)(&Ads[cur][rl * BK + ((q ^ (c & 3)) * 8)]);
        }
#pragma unroll
        for (int i = 0; i < MI; ++i)
#pragma unroll
            for (int j = 0; j < NJ; ++j)
                acc[i][j] = __builtin_amdgcn_mfma_f32_16x16x32_bf16(afW[j], bfA[i],
                                                                    acc[i][j], 0, 0, 0);
        WAITCNT_LGKM0();
        S_BARRIER();
    }

    float alpha = (EPI == 1) ? *alpha_p : 0.f;
#pragma unroll
    for (int i = 0; i < MI; ++i) {
        const int rowg = row0 + wr * WM + i * 16 + c;
        if (EPI == 0) {
#pragma unroll
            for (int j = 0; j < NJ; ++j) {
                const int colb = col0 + wc * WN + j * 16 + q * 4;
                const f32x4 bv = *(const f32x4*)(bias + colb);
                float v0 = acc[i][j][0] + bv[0];
                float v1 = acc[i][j][1] + bv[1];
                float v2 = acc[i][j][2] + bv[2];
                float v3 = acc[i][j][3] + bv[3];
                const size_t idx = (size_t)rowg * N + colb;
                bf16x4 o;
                o[0] = (__bf16)(v0 / (1.f + __expf(-v0)));
                o[1] = (__bf16)(v1 / (1.f + __expf(-v1)));
                o[2] = (__bf16)(v2 / (1.f + __expf(-v2)));
                o[3] = (__bf16)(v3 / (1.f + __expf(-v3)));
                __builtin_nontemporal_store(o, (bf16x4*)((__bf16*)Cout + idx));
            }
        } else {
            f32x4 hv[NJ];
#pragma unroll
            for (int j = 0; j < NJ; ++j) {
                const int colb = col0 + wc * WN + j * 16 + q * 4;
                hv[j] = __builtin_nontemporal_load(
                    (const f32x4*)(hid + (size_t)rowg * N + colb));
            }
#pragma unroll
            for (int j = 0; j < NJ; ++j) {
                const int colb = col0 + wc * WN + j * 16 + q * 4;
                const f32x4 bv = *(const f32x4*)(bias + colb);
                float v0 = acc[i][j][0] + bv[0];
                float v1 = acc[i][j][1] + bv[1];
                float v2 = acc[i][j][2] + bv[2];
                float v3 = acc[i][j][3] + bv[3];
                f32x4 o;
                o[0] = hv[j][0] + alpha * (v0 - hv[j][0]);
                o[1] = hv[j][1] + alpha * (v1 - hv[j][1]);
                o[2] = hv[j][2] + alpha * (v2 - hv[j][2]);
                o[3] = hv[j][3] + alpha * (v3 - hv[j][3]);
                __builtin_nontemporal_store(
                    o, (f32x4*)((float*)Cout + (size_t)rowg * N + colb));
            }
        }
    }
}

// ---------------------------------------------------------------------------
// Launch
// ---------------------------------------------------------------------------
extern "C" void kernel_launch(void* const* d_in, const int* in_sizes, int n_in,
                              void* d_out, int out_size, void* d_ws, size_t ws_size,
                              hipStream_t stream) {
    const float* hidden = (const float*)d_in[0];
    const float* ln_gamma = (const float*)d_in[1];
    const float* ln_beta = (const float*)d_in[2];
    const float* W_down = (const float*)d_in[3];
    const float* b_down = (const float*)d_in[4];
    const float* W_up = (const float*)d_in[5];
    const float* b_up = (const float*)d_in[6];
    const float* alpha = (const float*)d_in[7];
    float* out = (float*)d_out;

    const int D = in_sizes[2];      // 2048
    const int Db = in_sizes[4];     // 512
    const int M = in_sizes[0] / D;  // 16384

    char* w = (char*)d_ws;
    __bf16* z = (__bf16*)w;   w += (size_t)M * Db * sizeof(__bf16);
    __bf16* Wtd = (__bf16*)w; w += (size_t)D * Db * sizeof(__bf16);  // [Db][D]
    __bf16* Wtu = (__bf16*)w; w += (size_t)Db * D * sizeof(__bf16);  // [D][Db]
    float* C1 = (float*)w;    w += Db * sizeof(float);
    float* C2b = (float*)w;   w += Db * sizeof(float);

    (void)hipMemsetAsync(C1, 0, Db * sizeof(float), stream);
    (void)hipMemcpyAsync(C2b, b_down, Db * sizeof(float), hipMemcpyDeviceToDevice, stream);

    const int ntiles = 2 * (D / 32) * (Db / 32);
    prep_w_kernel<<<ntiles, 256, 0, stream>>>(W_down, Wtd, W_up, Wtu,
                                              ln_gamma, ln_beta, C1, C2b, D, Db);

    // fused LN + down-proj + SiLU: raw fp32 hidden (nt) in, bf16 z (nt) out.
    fused_ln_down<<<dim3(Db / 128, M / 64), 256, 0, stream>>>(
        hidden, Wtd, C1, C2b, z, M, Db, D);

    // up-proj + residual: nt hid/out keeps z and Wtu L2-resident.
    gemm_bt<1, 128, 128, 4><<<dim3(D / 128, M / 128), 256, 0, stream>>>(
        z, Wtu, b_up, hidden, alpha, (void*)out, M, D, Db);
}

// Round 8
// 411.412 us; speedup vs baseline: 1.1587x; 1.1587x over previous
//
#include <hip/hip_runtime.h>

typedef __bf16 bf16x8 __attribute__((ext_vector_type(8)));
typedef __bf16 bf16x4 __attribute__((ext_vector_type(4)));
typedef float f32x4 __attribute__((ext_vector_type(4)));

#define S_BARRIER() asm volatile("s_barrier" ::: "memory")
#define WAITCNT_VM(n) asm volatile("s_waitcnt vmcnt(" #n ")" ::: "memory")
#define WAITCNT_LGKM0() asm volatile("s_waitcnt lgkmcnt(0)" ::: "memory")

// ---------------------------------------------------------------------------
// Weight prep (LN fused into down-proj GEMM).
// Blocks [0, ntile_d): W_down transpose with gamma folded: Wtd[n][k] =
//   bf16(gamma[k]*Wd[k][n]);  C1[n] += sum_k float(bf16(gamma[k]*W[k][n]));
//   C2w[n] += sum_k beta[k]*W[k][n]   (both zero-initialized; b_down is
//   added in the fused epilogue -> no memcpy dispatch needed).
// Blocks [ntile_d, 2*ntile_d): plain W_up transpose -> bf16 Wtu[d][k].
// ---------------------------------------------------------------------------
__global__ __launch_bounds__(256) void prep_w_kernel(
    const float* __restrict__ Wd, __bf16* __restrict__ Wtd,
    const float* __restrict__ Wu, __bf16* __restrict__ Wtu,
    const float* __restrict__ g, const float* __restrict__ be,
    float* __restrict__ C1, float* __restrict__ C2w,
    int D, int Db) {
    const int ntile_d = (Db / 32) * (D / 32);
    __shared__ float t[32][33];
    const int c = threadIdx.x & 31, r0 = threadIdx.x >> 5;
    if ((int)blockIdx.x < ntile_d) {
        const int K = D, N = Db, tile = blockIdx.x;
        const int tn = tile % (N / 32), tk = tile / (N / 32);
        const int n0 = tn * 32, k0 = tk * 32;
#pragma unroll
        for (int r = r0; r < 32; r += 8)
            t[r][c] = Wd[(size_t)(k0 + r) * N + n0 + c];
        __syncthreads();
        const float gv = g[k0 + c];
        const float bv = be[k0 + c];
        float c1p[4], c2p[4];
#pragma unroll
        for (int u = 0; u < 4; ++u) {
            const int r = r0 + u * 8;
            const float wv = t[c][r];
            const __bf16 w16 = (__bf16)(gv * wv);
            Wtd[(size_t)(n0 + r) * K + k0 + c] = w16;
            c1p[u] = (float)w16;
            c2p[u] = bv * wv;
        }
#pragma unroll
        for (int o = 16; o > 0; o >>= 1)
#pragma unroll
            for (int u = 0; u < 4; ++u) {
                c1p[u] += __shfl_xor(c1p[u], o);
                c2p[u] += __shfl_xor(c2p[u], o);
            }
        if (c == 0)
#pragma unroll
            for (int u = 0; u < 4; ++u) {
                atomicAdd(&C1[n0 + r0 + u * 8], c1p[u]);
                atomicAdd(&C2w[n0 + r0 + u * 8], c2p[u]);
            }
    } else {
        const int K = Db, N = D, tile = blockIdx.x - ntile_d;
        const int tn = tile % (N / 32), tk = tile / (N / 32);
        const int n0 = tn * 32, k0 = tk * 32;
#pragma unroll
        for (int r = r0; r < 32; r += 8)
            t[r][c] = Wu[(size_t)(k0 + r) * N + n0 + c];
        __syncthreads();
#pragma unroll
        for (int r = r0; r < 32; r += 8)
            Wtu[(size_t)(n0 + r) * K + k0 + c] = (__bf16)t[c][r];
    }
}

// ---------------------------------------------------------------------------
// FUSED LayerNorm + down-proj + SiLU (r4 proven structure, BK=32) + XCD
// PANEL-AFFINITY SWIZZLE.
//   z = silu( rstd*acc - (rstd*mu)*C1[n] + C2w[n] + b_down[n] )
// r4/r7 PMC showed FETCH = X(134MB) + ~130MB WEIGHT RE-FETCH: 1024 blocks x
// 512KB panel = 512MB L2 demand, ~25% missing because every XCD cycles all
// 4 panels while the X stream churns its L2. Fix by construction: linear
// block id round-robins XCDs (id%8), so map  xcd=id&7 -> bn=xcd/2,
// bm=(xcd&1)*(nbm/2)+(id>>3).  Each XCD touches ONE 512KB panel (4x smaller
// weight working set per 4MB L2).  nt hints are dead (r7: FETCH/WRITE rose).
// - A reg-staged: 32B/lane/iter fp32 -> cast bf16 -> single-buffer LDS
//   (written+read inside same barrier pair).
// - B via global_load_lds dbuf (2 DMAs/wave/iter); vmcnt(4) keeps next
//   tile's 2 DMAs + 2 A-loads in flight across the barrier.
// - Row stats accumulate AFTER the MFMA block (off the critical path);
//   exact coverage: thread owns row arow, chunk (lane&3)^(lrow&3).
// - XOR chunk swizzle; operand-swap MFMA.
// 64x128 tile, 1024 blocks, ~21KB LDS -> 4 blocks/CU (grid-capped).
// ---------------------------------------------------------------------------
__global__ __launch_bounds__(256, 4) void fused_ln_down(
    const float* __restrict__ X, const __bf16* __restrict__ Bt,
    const float* __restrict__ C1, const float* __restrict__ C2w,
    const float* __restrict__ bd,
    __bf16* __restrict__ Z, int M, int N, int K) {
    constexpr int BM = 64, BN = 128, BK = 32;
    constexpr int WM = 32, WN = 64, MI = 2, NJ = 4;
    __shared__ __align__(16) __bf16 Ads[BM * BK];  // single buffer
    __shared__ __align__(16) __bf16 Bds[2][BN * BK];
    __shared__ float sRow[BM], ssRow[BM];

    const int tid = threadIdx.x;
    const int wave = tid >> 6, lane = tid & 63;

    // XCD panel-affinity swizzle (bijective; falls back to row-major)
    const int nbn = N / BN, nbm = M / BM;
    int bn, bm;
    {
        const int id = blockIdx.x;
        if (nbn <= 8 && (8 % nbn) == 0 && ((nbn * nbm) & 7) == 0 &&
            (nbm % (8 / nbn)) == 0) {
            const int per = 8 / nbn;  // XCDs per weight panel
            const int xcd = id & 7, slot = id >> 3;
            bn = xcd / per;
            bm = (xcd % per) * (nbm / per) + slot;
        } else {
            bn = id % nbn;
            bm = id / nbn;
        }
    }
    const int row0 = bm * BM, col0 = bn * BN;
    const int wr = wave >> 1, wc = wave & 1;

    f32x4 acc[MI][NJ] = {};

    const int lrow = lane >> 2;                 // 0..15
    const int chunk = (lane & 3) ^ (lrow & 3);  // global k-chunk staged
    const int arow = wave * 16 + lrow;          // 0..63: this thread's A row
    const float* Axr = X + (size_t)(row0 + arow) * K + chunk * 8;
    const __bf16* Bg = Bt + (size_t)col0 * K;
    const int lk = chunk * 8;

    const int c = lane & 15, q = lane >> 4;

    auto stageB = [&](int k0, int b) {
#pragma unroll
        for (int p = 0; p < 2; ++p) {
            const int r = wave * 32 + p * 16;  // wave-uniform B 16-row group
            __builtin_amdgcn_global_load_lds(
                (__attribute__((address_space(1))) void*)(Bg + (size_t)(r + lrow) * K + k0 + lk),
                (__attribute__((address_space(3))) void*)(&Bds[b][r * BK]),
                16, 0, 0);
        }
    };

    float s = 0.f, ss = 0.f;
    const int nk = K / BK;  // 64
    stageB(0, 0);
    f32x4 a0 = *(const f32x4*)(Axr);
    f32x4 a1 = *(const f32x4*)(Axr + 4);
    for (int it = 0; it < nk; ++it) {
        const int cur = it & 1;
        f32x4 n0, n1;
        if (it + 1 < nk) {
            stageB((it + 1) * BK, cur ^ 1);
            n0 = *(const f32x4*)(Axr + (it + 1) * BK);
            n1 = *(const f32x4*)(Axr + (it + 1) * BK + 4);
            WAITCNT_VM(4);  // next tile's 2 DMAs + 2 loads stay in flight
        } else {
            WAITCNT_VM(0);
        }
        // cast + LDS write of current A chunk (slot = lane&3)
        bf16x8 av;
        av[0] = (__bf16)a0[0]; av[1] = (__bf16)a0[1];
        av[2] = (__bf16)a0[2]; av[3] = (__bf16)a0[3];
        av[4] = (__bf16)a1[0]; av[5] = (__bf16)a1[1];
        av[6] = (__bf16)a1[2]; av[7] = (__bf16)a1[3];
        *(bf16x8*)(&Ads[arow * BK + (lane & 3) * 8]) = av;
        WAITCNT_LGKM0();  // my ds_write retired
        S_BARRIER();      // all waves: A written, B(cur) DMA landed

        bf16x8 afW[NJ], bfA[MI];
#pragma unroll
        for (int j = 0; j < NJ; ++j) {
            const int rl = wc * WN + j * 16 + c;
            afW[j] = *(const bf16x8*)(&Bds[cur][rl * BK + ((q ^ (c & 3)) * 8)]);
        }
#pragma unroll
        for (int i = 0; i < MI; ++i) {
            const int rl = wr * WM + i * 16 + c;
            bfA[i] = *(const bf16x8*)(&Ads[rl * BK + ((q ^ (c & 3)) * 8)]);
        }
#pragma unroll
        for (int i = 0; i < MI; ++i)
#pragma unroll
            for (int j = 0; j < NJ; ++j)
                acc[i][j] = __builtin_amdgcn_mfma_f32_16x16x32_bf16(afW[j], bfA[i],
                                                                    acc[i][j], 0, 0, 0);
        // stats AFTER MFMA issue: independent VALU, overlaps matrix pipe
        s += a0[0] + a0[1] + a0[2] + a0[3] + a1[0] + a1[1] + a1[2] + a1[3];
        ss += a0[0] * a0[0] + a0[1] * a0[1] + a0[2] * a0[2] + a0[3] * a0[3] +
              a1[0] * a1[0] + a1[1] * a1[1] + a1[2] * a1[2] + a1[3] * a1[3];
        WAITCNT_LGKM0();  // my LDS reads retired
        S_BARRIER();      // buffers safe to overwrite next iteration
        a0 = n0; a1 = n1;
    }

    // finalize row stats: reduce over lane bits 0-1 (the 4 chunk-lanes)
    s += __shfl_xor(s, 1);  s += __shfl_xor(s, 2);
    ss += __shfl_xor(ss, 1); ss += __shfl_xor(ss, 2);
    if ((lane & 3) == 0) { sRow[arow] = s; ssRow[arow] = ss; }
    __syncthreads();

    const float rK = 1.f / (float)K;
#pragma unroll
    for (int i = 0; i < MI; ++i) {
        const int rl = wr * WM + i * 16 + c;
        const float mu = sRow[rl] * rK;
        const float var = ssRow[rl] * rK - mu * mu;
        const float rstd = rsqrtf(var + 1e-5f);
        const float mrs = mu * rstd;
        const int rowg = row0 + rl;
#pragma unroll
        for (int j = 0; j < NJ; ++j) {
            const int colb = col0 + wc * WN + j * 16 + q * 4;
            const f32x4 c1 = *(const f32x4*)(C1 + colb);
            const f32x4 c2 = *(const f32x4*)(C2w + colb);
            const f32x4 bb = *(const f32x4*)(bd + colb);
            float v0 = rstd * acc[i][j][0] - mrs * c1[0] + c2[0] + bb[0];
            float v1 = rstd * acc[i][j][1] - mrs * c1[1] + c2[1] + bb[1];
            float v2 = rstd * acc[i][j][2] - mrs * c1[2] + c2[2] + bb[2];
            float v3 = rstd * acc[i][j][3] - mrs * c1[3] + c2[3] + bb[3];
            bf16x4 o;
            o[0] = (__bf16)(v0 / (1.f + __expf(-v0)));
            o[1] = (__bf16)(v1 / (1.f + __expf(-v1)));
            o[2] = (__bf16)(v2 / (1.f + __expf(-v2)));
            o[3] = (__bf16)(v3 / (1.f + __expf(-v3)));
            *(bf16x4*)(Z + (size_t)rowg * N + colb) = o;
        }
    }
}

// ---------------------------------------------------------------------------
// Up-proj GEMM (r3 proven, 96us): BK=32 dbuf LDS global_load_lds schedule,
// XOR chunk swizzle, operand-swap MFMA, residual fp32 epilogue with hoisted
// hid loads. Plain loads/stores (nt hints regressed in r7).
// ---------------------------------------------------------------------------
template <int EPI, int BM, int BN, int MINW>
__global__ __launch_bounds__(256, MINW) void gemm_bt(
    const __bf16* __restrict__ A, const __bf16* __restrict__ Bt,
    const float* __restrict__ bias, const float* __restrict__ hid,
    const float* __restrict__ alpha_p, void* __restrict__ Cout,
    int M, int N, int K) {
    constexpr int BK = 32;
    constexpr int WM = BM / 2, WN = BN / 2;
    constexpr int MI = WM / 16, NJ = WN / 16;
    constexpr int GA = BM / 64, GB = BN / 64;
    constexpr int L = GA + GB;
    __shared__ __align__(16) __bf16 Ads[2][BM * BK];
    __shared__ __align__(16) __bf16 Bds[2][BN * BK];

    const int tid = threadIdx.x;
    const int wave = tid >> 6;
    const int lane = tid & 63;
    const int bn = blockIdx.x, bm = blockIdx.y;
    const int row0 = bm * BM, col0 = bn * BN;
    const int wr = wave >> 1, wc = wave & 1;

    f32x4 acc[MI][NJ] = {};

    const __bf16* Ag = A + (size_t)row0 * K;
    const __bf16* Bg = Bt + (size_t)col0 * K;
    const int lrow = lane >> 2;
    const int lk = ((lane & 3) ^ (lrow & 3)) * 8;

    const int c = lane & 15;
    const int q = lane >> 4;

    auto stage = [&](int k0, int b) {
#pragma unroll
        for (int p = 0; p < GA; ++p) {
            const int r = wave * (16 * GA) + p * 16;
            __builtin_amdgcn_global_load_lds(
                (__attribute__((address_space(1))) void*)(Ag + (size_t)(r + lrow) * K + k0 + lk),
                (__attribute__((address_space(3))) void*)(&Ads[b][r * BK]),
                16, 0, 0);
        }
#pragma unroll
        for (int p = 0; p < GB; ++p) {
            const int r = wave * (16 * GB) + p * 16;
            __builtin_amdgcn_global_load_lds(
                (__attribute__((address_space(1))) void*)(Bg + (size_t)(r + lrow) * K + k0 + lk),
                (__attribute__((address_space(3))) void*)(&Bds[b][r * BK]),
                16, 0, 0);
        }
    };

    const int nk = K / BK;
    stage(0, 0);
    for (int it = 0; it < nk; ++it) {
        const int cur = it & 1;
        if (it + 1 < nk) {
            stage((it + 1) * BK, cur ^ 1);
            if constexpr (L == 3) WAITCNT_VM(3); else WAITCNT_VM(4);
        } else {
            WAITCNT_VM(0);
        }
        S_BARRIER();

        bf16x8 afW[NJ], bfA[MI];
#pragma unroll
        for (int j = 0; j < NJ; ++j) {
            const int rl = wc * WN + j * 16 + c;
            afW[j] = *(const bf16x8*)(&Bds[cur][rl * BK + ((q ^ (c & 3)) * 8)]);
        }
#pragma unroll
        for (int i = 0; i < MI; ++i) {
            const int rl = wr * WM + i * 16 + c;
            bfA[i] = *(const bf16x8*)(&Ads[cur][rl * BK + ((q ^ (c & 3)) * 8)]);
        }
#pragma unroll
        for (int i = 0; i < MI; ++i)
#pragma unroll
            for (int j = 0; j < NJ; ++j)
                acc[i][j] = __builtin_amdgcn_mfma_f32_16x16x32_bf16(afW[j], bfA[i],
                                                                    acc[i][j], 0, 0, 0);
        WAITCNT_LGKM0();
        S_BARRIER();
    }

    float alpha = (EPI == 1) ? *alpha_p : 0.f;
#pragma unroll
    for (int i = 0; i < MI; ++i) {
        const int rowg = row0 + wr * WM + i * 16 + c;
        if (EPI == 0) {
#pragma unroll
            for (int j = 0; j < NJ; ++j) {
                const int colb = col0 + wc * WN + j * 16 + q * 4;
                const f32x4 bv = *(const f32x4*)(bias + colb);
                float v0 = acc[i][j][0] + bv[0];
                float v1 = acc[i][j][1] + bv[1];
                float v2 = acc[i][j][2] + bv[2];
                float v3 = acc[i][j][3] + bv[3];
                const size_t idx = (size_t)rowg * N + colb;
                bf16x4 o;
                o[0] = (__bf16)(v0 / (1.f + __expf(-v0)));
                o[1] = (__bf16)(v1 / (1.f + __expf(-v1)));
                o[2] = (__bf16)(v2 / (1.f + __expf(-v2)));
                o[3] = (__bf16)(v3 / (1.f + __expf(-v3)));
                *(bf16x4*)((__bf16*)Cout + idx) = o;
            }
        } else {
            f32x4 hv[NJ];
#pragma unroll
            for (int j = 0; j < NJ; ++j) {
                const int colb = col0 + wc * WN + j * 16 + q * 4;
                hv[j] = *(const f32x4*)(hid + (size_t)rowg * N + colb);
            }
#pragma unroll
            for (int j = 0; j < NJ; ++j) {
                const int colb = col0 + wc * WN + j * 16 + q * 4;
                const f32x4 bv = *(const f32x4*)(bias + colb);
                float v0 = acc[i][j][0] + bv[0];
                float v1 = acc[i][j][1] + bv[1];
                float v2 = acc[i][j][2] + bv[2];
                float v3 = acc[i][j][3] + bv[3];
                f32x4 o;
                o[0] = hv[j][0] + alpha * (v0 - hv[j][0]);
                o[1] = hv[j][1] + alpha * (v1 - hv[j][1]);
                o[2] = hv[j][2] + alpha * (v2 - hv[j][2]);
                o[3] = hv[j][3] + alpha * (v3 - hv[j][3]);
                *(f32x4*)((float*)Cout + (size_t)rowg * N + colb) = o;
            }
        }
    }
}

// ---------------------------------------------------------------------------
// Launch
// ---------------------------------------------------------------------------
extern "C" void kernel_launch(void* const* d_in, const int* in_sizes, int n_in,
                              void* d_out, int out_size, void* d_ws, size_t ws_size,
                              hipStream_t stream) {
    const float* hidden = (const float*)d_in[0];
    const float* ln_gamma = (const float*)d_in[1];
    const float* ln_beta = (const float*)d_in[2];
    const float* W_down = (const float*)d_in[3];
    const float* b_down = (const float*)d_in[4];
    const float* W_up = (const float*)d_in[5];
    const float* b_up = (const float*)d_in[6];
    const float* alpha = (const float*)d_in[7];
    float* out = (float*)d_out;

    const int D = in_sizes[2];      // 2048
    const int Db = in_sizes[4];     // 512
    const int M = in_sizes[0] / D;  // 16384

    char* w = (char*)d_ws;
    __bf16* z = (__bf16*)w;   w += (size_t)M * Db * sizeof(__bf16);
    __bf16* Wtd = (__bf16*)w; w += (size_t)D * Db * sizeof(__bf16);  // [Db][D]
    __bf16* Wtu = (__bf16*)w; w += (size_t)Db * D * sizeof(__bf16);  // [D][Db]
    float* C1 = (float*)w;    w += Db * sizeof(float);
    float* C2w = (float*)w;   w += Db * sizeof(float);

    // zero C1 and C2w in one memset (adjacent in workspace)
    (void)hipMemsetAsync(C1, 0, 2 * Db * sizeof(float), stream);

    const int ntiles = 2 * (D / 32) * (Db / 32);
    prep_w_kernel<<<ntiles, 256, 0, stream>>>(W_down, Wtd, W_up, Wtu,
                                              ln_gamma, ln_beta, C1, C2w, D, Db);

    // fused LN + down-proj + SiLU, XCD panel-affinity swizzled grid.
    fused_ln_down<<<(M / 64) * (Db / 128), 256, 0, stream>>>(
        hidden, Wtd, C1, C2w, b_down, z, M, Db, D);

    // up-proj + residual (r3-proven).
    gemm_bt<1, 128, 128, 4><<<dim3(D / 128, M / 128), 256, 0, stream>>>(
        z, Wtu, b_up, hidden, alpha, (void*)out, M, D, Db);
}